// Round 5
// baseline (29921.262 us; speedup 1.0000x reference)
//
#include <hip/hip_runtime.h>
#include <cmath>
#include <cstring>

#define T_STEPS 8192
#define HDIM    2048
#define DIN     128
#define DOUT    128
#define NB      128         // reservoir blocks (16 rows each)
#define BT      512         // threads per reservoir block (8 waves)

// Epoch encoding: published = tanh(nh) + (epoch ? +EOFF : -EOFF).
// Accept: epoch ? (v >= ETHR) : (v <= -ETHR). fast_tanh may exceed |1| by a
// few ulp (v_rcp is approximate) -> need ETHR margin >> ulp. EOFF-1 > ETHR
// and ETHR > 1 + slop. EOFF=4, ETHR=2.5 gives ~1.5 margin both sides.
#define EOFF 4.0f
#define ETHR 2.5f

__device__ __forceinline__ unsigned long long agent_load8(const unsigned long long* p) {
    return __hip_atomic_load(p, __ATOMIC_RELAXED, __HIP_MEMORY_SCOPE_AGENT);
}
__device__ __forceinline__ void agent_store8(unsigned long long* p, unsigned long long v) {
    __hip_atomic_store(p, v, __ATOMIC_RELAXED, __HIP_MEMORY_SCOPE_AGENT);
}
// tanh via exp2+rcp: ~4 VALU ops instead of libm tanhf. May exceed |1| by a
// few ulp — protocol margins absorb that (EOFF/ETHR above).
__device__ __forceinline__ float fast_tanh(float x) {
    float t = __builtin_amdgcn_exp2f(fminf(x * 2.885390082f, 87.0f));
    return (t - 1.0f) * __builtin_amdgcn_rcpf(t + 1.0f);
}

// ---------------------------------------------------------------------------
// Prefill: slot1 = +EOFF (encoded act_{-1}=0, epoch 1), slot0 = 0 (neutral:
// rejected by both epoch predicates). Runs every call -> deterministic
// across graph replays.
// ---------------------------------------------------------------------------
__global__ void prefill_kernel(float* __restrict__ act_buf) {
    int i = blockIdx.x * blockDim.x + threadIdx.x;
    if (i < HDIM) {
        act_buf[i]        = 0.0f;
        act_buf[HDIM + i] = EOFF;
    }
}

// ---------------------------------------------------------------------------
// Kernel A: X[t][h] = sum_d inp[t][d] * w_ih[h][d] + b_ih[h]
// ---------------------------------------------------------------------------
__global__ __launch_bounds__(256) void inp_proj_kernel(
    const float* __restrict__ inp, const float* __restrict__ w_ih,
    const float* __restrict__ b_ih, float* __restrict__ X)
{
    __shared__ float As[64][65];
    __shared__ float Bs[64][65];
    const int tid = threadIdx.x;
    const int i0 = blockIdx.x * 64;   // t
    const int j0 = blockIdx.y * 64;   // h
    const int tx = tid % 16, ty = tid / 16;
    float acc[4][4] = {};
    for (int k0 = 0; k0 < DIN; k0 += 64) {
        for (int idx = tid; idx < 64 * 64; idx += 256) {
            int kk = idx % 64, ii = idx / 64;
            As[ii][kk] = inp[(size_t)(i0 + ii) * DIN + k0 + kk];
            Bs[ii][kk] = w_ih[(size_t)(j0 + ii) * DIN + k0 + kk];
        }
        __syncthreads();
        for (int kk = 0; kk < 64; ++kk) {
            float a[4], b[4];
#pragma unroll
            for (int u = 0; u < 4; ++u) a[u] = As[ty * 4 + u][kk];
#pragma unroll
            for (int v = 0; v < 4; ++v) b[v] = Bs[tx * 4 + v][kk];
#pragma unroll
            for (int u = 0; u < 4; ++u)
#pragma unroll
                for (int v = 0; v < 4; ++v) acc[u][v] += a[u] * b[v];
        }
        __syncthreads();
    }
#pragma unroll
    for (int u = 0; u < 4; ++u)
#pragma unroll
        for (int v = 0; v < 4; ++v)
            X[(size_t)(i0 + ty * 4 + u) * HDIM + j0 + tx * 4 + v] =
                acc[u][v] + b_ih[j0 + tx * 4 + v];
}

// ---------------------------------------------------------------------------
// Kernel B: reservoir recurrence. 128 blocks x 512 threads (8 waves).
// Wave w of block b owns rows r0 = b*16 + 2w, r0+1. W held as 64 floats/lane:
//   w0[j],w1[j] = W[r0 / r0+1] float2 at col-pair (lane + 64*j).
// Per step: 2x 8B epoch-encoded agent polls (data IS the flag) -> LDS ->
// sync -> 16 ds_read_b64 + 64 FMA -> 64-lane butterfly -> publish FIRST.
// X u-reads / nh-writes batched in 64-step register windows (lane t&63 owns
// step t's values) so no X HBM op sits in the per-step vmcnt chain.
// ---------------------------------------------------------------------------
__global__ __launch_bounds__(BT, 1) void reservoir_kernel(
    const float* __restrict__ w_hh, float* __restrict__ X,
    float* __restrict__ act_buf)
{
    const int b    = blockIdx.x;
    const int tid  = threadIdx.x;
    const int wave = tid >> 6;            // 0..7
    const int lane = tid & 63;
    const int r0   = b * 16 + wave * 2;   // row pair (r0, r0+1)

    float2 w0[16], w1[16];
    {
        const float2* p0 = (const float2*)(w_hh + (size_t)r0 * HDIM);
        const float2* p1 = (const float2*)(w_hh + (size_t)(r0 + 1) * HDIM);
#pragma unroll
        for (int j = 0; j < 16; ++j) {
            w0[j] = p0[lane + 64 * j];
            w1[j] = p1[lane + 64 * j];
        }
    }
#pragma unroll
    for (int j = 0; j < 16; ++j) {
        asm volatile("" : "+v"(w0[j].x), "+v"(w0[j].y),
                          "+v"(w1[j].x), "+v"(w1[j].y));
    }

    __shared__ float2 lds[2][HDIM / 2];

    float2* X2 = (float2*)X;              // float2 view, 1024 per row
    const int rc = r0 >> 1;               // this wave's float2 column in X2

    float2 u_buf = make_float2(0.0f, 0.0f);  // u for step (window+lane)
    float2 x_buf = make_float2(0.0f, 0.0f);  // nh produced at step (window+lane)

    for (int t = 0; t < T_STEPS; ++t) {
        // ---- window boundary: batch X I/O (off the per-step chain) ----
        if ((t & 63) == 0) {
            if (t) {  // store previous window's nh pairs
                X2[(size_t)(t - 64 + lane) * (HDIM / 2) + rc] = x_buf;
            }
            u_buf = X2[(size_t)(t + lane) * (HDIM / 2) + rc];  // u for t..t+63
        }

        // ---- consume act_{t-1}: slot (t+1)&1, epoch ((t+3)>>1)&1 ----
        const int   s   = (t + 1) & 1;
        const int   e   = ((t + 3) >> 1) & 1;
        const float off = e ? EOFF : -EOFF;
        const unsigned long long* src =
            (const unsigned long long*)(act_buf + (size_t)s * HDIM);

        unsigned long long v0, v1;
        bool q0 = false, q1 = false;
        do {
            if (!q0) {
                v0 = agent_load8(src + tid);
                float2 f; memcpy(&f, &v0, 8);
                q0 = e ? (f.x >= ETHR && f.y >= ETHR)
                       : (f.x <= -ETHR && f.y <= -ETHR);
            }
            if (!q1) {
                v1 = agent_load8(src + tid + BT);
                float2 f; memcpy(&f, &v1, 8);
                q1 = e ? (f.x >= ETHR && f.y >= ETHR)
                       : (f.x <= -ETHR && f.y <= -ETHR);
            }
        } while (!(q0 && q1));

        const int ls = t & 1;
        {
            float2 f0, f1; memcpy(&f0, &v0, 8); memcpy(&f1, &v1, 8);
            f0.x -= off; f0.y -= off; f1.x -= off; f1.y -= off;
            lds[ls][tid]      = f0;
            lds[ls][tid + BT] = f1;
        }
        __syncthreads();

        // ---- dot: 16 ds_read_b64, 64 FMA ----
        const float2* a = lds[ls];
        float s0 = 0.0f, s1 = 0.0f;
#pragma unroll
        for (int j = 0; j < 16; ++j) {
            float2 av = a[lane + 64 * j];
            s0 += w0[j].x * av.x + w0[j].y * av.y;
            s1 += w1[j].x * av.x + w1[j].y * av.y;
        }
#pragma unroll
        for (int o = 32; o > 0; o >>= 1) {
            s0 += __shfl_xor(s0, o, 64);
            s1 += __shfl_xor(s1, o, 64);
        }
        // all lanes now hold the full sums
        const int   step = t & 63;
        const float ux   = __shfl(u_buf.x, step, 64);
        const float uy   = __shfl(u_buf.y, step, 64);
        const float nh0  = ux + s0;
        const float nh1  = uy + s1;

        // ---- publish FIRST (critical path), then buffer nh ----
        if (lane == 0) {
            const float poff = ((t >> 1) & 1) ? EOFF : -EOFF;
            float2 na = make_float2(fast_tanh(nh0) + poff, fast_tanh(nh1) + poff);
            unsigned long long pv; memcpy(&pv, &na, 8);
            agent_store8((unsigned long long*)(act_buf + (size_t)(t & 1) * HDIM)
                             + (b * 8 + wave), pv);
        }
        if (lane == step) x_buf = make_float2(nh0, nh1);
    }
    // flush last window
    X2[(size_t)(T_STEPS - 64 + lane) * (HDIM / 2) + rc] = x_buf;
}

// ---------------------------------------------------------------------------
// Kernel C: C[i][j] = sum_{t=start}^{T-1} A[t][i] * B[t][j]
// ---------------------------------------------------------------------------
__global__ __launch_bounds__(256) void atb_kernel(
    const float* __restrict__ A, const float* __restrict__ B,
    float* __restrict__ C, int M, int N, const int* __restrict__ washout_p)
{
    const int w = *washout_p;
    const int start = (T_STEPS > 4 * w) ? w : 0;

    __shared__ float As[32][64];
    __shared__ float Bs[32][64];
    const int tid = threadIdx.x;
    const int i0 = blockIdx.x * 64;
    const int j0 = blockIdx.y * 64;
    const int tx = tid % 16, ty = tid / 16;
    float acc[4][4] = {};

    for (int t0 = start; t0 < T_STEPS; t0 += 32) {
        for (int idx = tid; idx < 32 * 64; idx += 256) {
            int ii = idx % 64, tt = idx / 64;
            int t = t0 + tt;
            As[tt][ii] = (t < T_STEPS) ? A[(size_t)t * M + i0 + ii] : 0.0f;
            Bs[tt][ii] = (t < T_STEPS && (j0 + ii) < N)
                             ? B[(size_t)t * N + j0 + ii] : 0.0f;
        }
        __syncthreads();
        for (int tt = 0; tt < 32; ++tt) {
            float a[4], bb[4];
#pragma unroll
            for (int u = 0; u < 4; ++u) a[u] = As[tt][ty * 4 + u];
#pragma unroll
            for (int v = 0; v < 4; ++v) bb[v] = Bs[tt][tx * 4 + v];
#pragma unroll
            for (int u = 0; u < 4; ++u)
#pragma unroll
                for (int v = 0; v < 4; ++v) acc[u][v] += a[u] * bb[v];
        }
        __syncthreads();
    }
#pragma unroll
    for (int u = 0; u < 4; ++u)
#pragma unroll
        for (int v = 0; v < 4; ++v) {
            int i = i0 + ty * 4 + u, j = j0 + tx * 4 + v;
            if (j < N) C[(size_t)i * N + j] = acc[u][v];
        }
}

// ---------------------------------------------------------------------------
extern "C" void kernel_launch(void* const* d_in, const int* in_sizes, int n_in,
                              void* d_out, int out_size, void* d_ws, size_t ws_size,
                              hipStream_t stream)
{
    const float* inp     = (const float*)d_in[0];   // 8192x128
    const float* target  = (const float*)d_in[1];   // 8192x128
    const float* w_ih    = (const float*)d_in[2];   // 2048x128
    const float* b_ih    = (const float*)d_in[3];   // 2048
    const float* w_hh    = (const float*)d_in[4];   // 2048x2048
    const int*   washout = (const int*)d_in[5];     // scalar

    float* out = (float*)d_out;                  // HTH (2048x2048) ++ HTY (2048x128)
    float* X       = (float*)d_ws;               // 8192x2048 (inp_proj -> all_hid)
    float* act_buf = X + (size_t)T_STEPS * HDIM; // 2x2048

    prefill_kernel<<<dim3(8), dim3(256), 0, stream>>>(act_buf);

    inp_proj_kernel<<<dim3(T_STEPS / 64, HDIM / 64), dim3(256), 0, stream>>>(
        inp, w_ih, b_ih, X);

    reservoir_kernel<<<dim3(NB), dim3(BT), 0, stream>>>(w_hh, X, act_buf);

    atb_kernel<<<dim3(HDIM / 64, HDIM / 64), dim3(256), 0, stream>>>(
        X, X, out, HDIM, HDIM, washout);
    atb_kernel<<<dim3(HDIM / 64, DOUT / 64), dim3(256), 0, stream>>>(
        X, target, out + (size_t)HDIM * HDIM, HDIM, DOUT, washout);
}